// Round 6
// baseline (629.016 us; speedup 1.0000x reference)
//
#include <hip/hip_runtime.h>
#include <math.h>

typedef unsigned short u16;
typedef short s16x8 __attribute__((ext_vector_type(8)));
typedef short s16x4 __attribute__((ext_vector_type(4)));
typedef float f32x4 __attribute__((ext_vector_type(4)));
typedef u16 u16x4 __attribute__((ext_vector_type(4)));

// ---------------- workspace layout (bytes) ----------------
// XB   : x bf16 [4096][2048]               16,777,216  (reused as QH [16][4096][128])
// WQKV : qkv weights bf16 [3072][2048]     12,582,912  (region reused after gemm1:
//          KH bf16 [4][64][4][64][32] @ +0 (4 MB)  -- K tiled [t][kc][kr][c]
//          VT bf16 [4][64][128][64] @ +4,194,304 (4 MB) -- V^T tiled, permuted+xor-swizzled
//          ML f32 [16*79][128][2]  @ +8,388,608 (1,294,336 B))
// WP   : proj weights bf16 [2048][2048]     8,388,608
// QKV  : fp32 [4096][3072]                 50,331,648  (reused: Opart bf16 1264x[128][128] = 41,418,752)
// Y    : bf16 [4096][2048] @ 79,691,776    16,777,216
static constexpr size_t OFF_XB   = 0;
static constexpr size_t OFF_WQKV = 16777216;
static constexpr size_t OFF_KH   = 16777216;
static constexpr size_t OFF_VT   = 20971520;
static constexpr size_t OFF_ML   = 25165824;
static constexpr size_t OFF_WP   = 29360128;
static constexpr size_t OFF_QKV  = 37748736;
static constexpr size_t OFF_Y    = 79691776;

__device__ __forceinline__ u16 f2bf(float f) {
  union { float f; unsigned u; } v; v.f = f;
  unsigned r = v.u + 0x7fffu + ((v.u >> 16) & 1u);   // RNE
  return (u16)(r >> 16);
}

__device__ __forceinline__ float bf2f(u16 b) {
  union { unsigned u; float f; } v; v.u = ((unsigned)b) << 16;
  return v.f;
}

__device__ __forceinline__ void async16(const u16* g, u16* lds) {
  __builtin_amdgcn_global_load_lds(
      (const __attribute__((address_space(1))) void*)g,
      (__attribute__((address_space(3))) void*)lds, 16, 0, 0);
}

// ---------------- bitlinear weight quantization (fused, 5120 rows) ----------
__global__ __launch_bounds__(256) void quant_all(const float* __restrict__ wq,
                                                 const float* __restrict__ wk,
                                                 const float* __restrict__ wv,
                                                 const float* __restrict__ wp,
                                                 u16* __restrict__ outqkv,
                                                 u16* __restrict__ outp) {
  const int row = blockIdx.x, tid = threadIdx.x;
  const float* src;
  u16* dst;
  if (row < 2048)      { src = wq + (size_t)row * 2048;          dst = outqkv + (size_t)row * 2048; }
  else if (row < 2560) { src = wk + (size_t)(row - 2048) * 2048; dst = outqkv + (size_t)row * 2048; }
  else if (row < 3072) { src = wv + (size_t)(row - 2560) * 2048; dst = outqkv + (size_t)row * 2048; }
  else                 { src = wp + (size_t)(row - 3072) * 2048; dst = outp + (size_t)(row - 3072) * 2048; }
  src += tid * 8;
  float4 a = *(const float4*)(src);
  float4 b = *(const float4*)(src + 4);
  float asum = fabsf(a.x)+fabsf(a.y)+fabsf(a.z)+fabsf(a.w)
             + fabsf(b.x)+fabsf(b.y)+fabsf(b.z)+fabsf(b.w);
  #pragma unroll
  for (int off = 1; off < 64; off <<= 1) asum += __shfl_xor(asum, off, 64);
  __shared__ float red[4];
  if ((tid & 63) == 0) red[tid >> 6] = asum;
  __syncthreads();
  float s = fmaxf((red[0]+red[1]+red[2]+red[3]) * (1.0f/2048.0f), 1e-5f);
  float v[8] = {a.x,a.y,a.z,a.w,b.x,b.y,b.z,b.w};
  u16* d = dst + tid * 8;
  #pragma unroll
  for (int i = 0; i < 8; i++) {
    float q = rintf(v[i] / s);
    q = fminf(fmaxf(q, -1.f), 1.f);
    d[i] = f2bf(q * s);
  }
}

// ---------------- fp32 -> bf16 ----------------
__global__ __launch_bounds__(256) void cvt_bf16(const float* __restrict__ in,
                                                u16* __restrict__ out) {
  size_t i = ((size_t)blockIdx.x * 256 + threadIdx.x) * 4;
  float4 v = *(const float4*)(in + i);
  u16x4 o;
  o.x = f2bf(v.x); o.y = f2bf(v.y); o.z = f2bf(v.z); o.w = f2bf(v.w);
  *(u16x4*)(out + i) = o;
}

// ---------------- GEMM  C[M][N] = A[M][K] * B[N][K]^T  (bf16 in, fp32 out) -------
__global__ __launch_bounds__(256) void gemm_bt(const u16* __restrict__ A,
                                               const u16* __restrict__ B,
                                               float* __restrict__ C,
                                               int M, int N, int K) {
  __shared__ u16 sA[128 * 32];
  __shared__ u16 sB[128 * 32];
  const int tid = threadIdx.x;
  const int lane = tid & 63;
  const int wid = tid >> 6;
  const int lr = lane & 15, lq = lane >> 4;
  const int wm = (wid >> 1) * 64, wn = (wid & 1) * 64;
  const size_t m0 = (size_t)blockIdx.y * 128, n0 = (size_t)blockIdx.x * 128;

  const int r0 = tid >> 2, c0 = (tid & 3) * 8;
  const u16* Ab0 = A + (m0 + r0) * (size_t)K + c0;
  const u16* Ab1 = A + (m0 + 64 + r0) * (size_t)K + c0;
  const u16* Bb0 = B + (n0 + r0) * (size_t)K + c0;
  const u16* Bb1 = B + (n0 + 64 + r0) * (size_t)K + c0;
  u16* sA0 = &sA[tid * 8];
  u16* sA1 = &sA[(256 + tid) * 8];
  u16* sB0 = &sB[tid * 8];
  u16* sB1 = &sB[(256 + tid) * 8];

  f32x4 acc[4][4] = {};

  for (int kt = 0; kt < K; kt += 32) {
    async16(Ab0 + kt, sA0);
    async16(Ab1 + kt, sA1);
    async16(Bb0 + kt, sB0);
    async16(Bb1 + kt, sB1);
    __syncthreads();
    s16x8 af[4], bf[4];
    #pragma unroll
    for (int mt = 0; mt < 4; mt++)
      af[mt] = *(const s16x8*)&sA[(wm + mt * 16 + lr) * 32 + lq * 8];
    #pragma unroll
    for (int nt = 0; nt < 4; nt++)
      bf[nt] = *(const s16x8*)&sB[(wn + nt * 16 + lr) * 32 + lq * 8];
    #pragma unroll
    for (int mt = 0; mt < 4; mt++)
      #pragma unroll
      for (int nt = 0; nt < 4; nt++)
        acc[mt][nt] = __builtin_amdgcn_mfma_f32_16x16x32_bf16(af[mt], bf[nt], acc[mt][nt], 0, 0, 0);
    __syncthreads();
  }
  #pragma unroll
  for (int mt = 0; mt < 4; mt++)
    #pragma unroll
    for (int nt = 0; nt < 4; nt++)
      #pragma unroll
      for (int r = 0; r < 4; r++) {
        size_t m = m0 + wm + mt * 16 + lq * 4 + r;
        size_t n = n0 + wn + nt * 16 + lr;
        C[m * (size_t)N + n] = acc[mt][nt][r];
      }
}

// ---------------- rmsnorm + rope; K written in attn-staging layout ----------
__global__ __launch_bounds__(256) void prep_qk(const float* __restrict__ qkv,
                                               const float* __restrict__ qgain,
                                               u16* __restrict__ Qh,
                                               u16* __restrict__ Kh) {
  const int s = blockIdx.y;
  const int j = blockIdx.x * 4 + (threadIdx.x >> 6);
  const int t = threadIdx.x & 63;
  const float* row = qkv + (size_t)s * 3072 + (size_t)j * 128;
  float x1 = row[t], x2 = row[t + 64];
  float ss = x1 * x1 + x2 * x2;
  #pragma unroll
  for (int off = 1; off < 64; off <<= 1) ss += __shfl_xor(ss, off, 64);
  float rn = rsqrtf(ss * (1.0f / 128.0f) + 1.1920929e-07f);
  float invf = exp2f(-(float)t * 0.20762050593048096f);  // log2(10000)/64
  float ang = (float)s * invf;
  float sn, c;
  sincosf(ang, &sn, &c);
  if (j < 16) {
    float g = qgain[j] * 0.12751738f;   // (1/sqrt(128)) * log2(e)
    float q1 = x1 * rn, q2 = x2 * rn;
    float o1 = (q1 * c + q2 * sn) * g;
    float o2 = (-q1 * sn + q2 * c) * g;
    u16* dst = Qh + ((size_t)j * 4096 + s) * 128;
    dst[t] = f2bf(o1); dst[t + 64] = f2bf(o2);
  } else {
    const int kvh = j - 16;
    float k1 = x1 * rn, k2 = x2 * rn;
    float o1 = k1 * c + k2 * sn;
    float o2 = -k1 * sn + k2 * c;
    // KH[kvh][tt][kc][kr][c32]: d=t -> kc=t>>5, d=t+64 -> kc=2+(t>>5)
    const int tt = s >> 6, kr = s & 63;
    u16* base = Kh + (((size_t)kvh * 64 + tt) * 4) * 2048 + kr * 32 + (t & 31);
    base[(size_t)(t >> 5) * 2048]       = f2bf(o1);
    base[(size_t)(2 + (t >> 5)) * 2048] = f2bf(o2);
  }
}

// ---------------- V transpose into attn-staging layout ----------------------
// VT[kvh][tt][d][64]: per (d, kv-tile) row of 64, kv permuted
// kv' = 16*((kv>>2)&3) + 4*(kv>>4) + (kv&3), then 16B-granules XORed by (d&7).
__global__ __launch_bounds__(256) void vtrans(const float* __restrict__ qkv,
                                              u16* __restrict__ Vtg) {
  __shared__ float tile[64][67];
  const int tid = threadIdx.x;
  const int s0 = blockIdx.y * 64;
  const int c0 = blockIdx.x * 64;
  #pragma unroll
  for (int it = 0; it < 4; it++) {
    int i = it * 256 + tid;
    int r = i >> 4, c = (i & 15) * 4;
    float4 v = *(const float4*)(qkv + (size_t)(s0 + r) * 3072 + 2560 + c0 + c);
    tile[r][c] = v.x; tile[r][c + 1] = v.y; tile[r][c + 2] = v.z; tile[r][c + 3] = v.w;
  }
  __syncthreads();
  #pragma unroll
  for (int it = 0; it < 2; it++) {
    int i = it * 256 + tid;
    int dl = i >> 3, sc = (i & 7) * 8;
    int cglob = c0 + dl;
    int kvh = cglob >> 7, d = cglob & 127;
    int tt = s0 >> 6;
    int a0 = 16 * ((sc >> 2) & 3) + 4 * (sc >> 4);
    int a1 = 16 * (((sc >> 2) + 1) & 3) + 4 * (sc >> 4);
    int x = d & 7;
    int p0 = ((((a0 >> 3) ^ x) << 3) | (a0 & 7));
    int p1 = ((((a1 >> 3) ^ x) << 3) | (a1 & 7));
    size_t rowbase = (((size_t)kvh * 64 + tt) * 128 + d) * 64;
    u16 lo[4], hi[4];
    #pragma unroll
    for (int jj = 0; jj < 4; jj++) lo[jj] = f2bf(tile[sc + jj][dl]);
    #pragma unroll
    for (int jj = 0; jj < 4; jj++) hi[jj] = f2bf(tile[sc + 4 + jj][dl]);
    *(s16x4*)&Vtg[rowbase + p0] = *(s16x4*)lo;
    *(s16x4*)&Vtg[rowbase + p1] = *(s16x4*)hi;
  }
}

// ---------------- flash attention v6 ----------------------------------------
// Uniform 16/17-step units (static tables), S^T form, P in registers.
// NEW: global_load_lds staging from pre-arranged K/V layouts (no ds_writes,
// conflict-free b128 reads), stale-max (margin 3, shuffle-free steady state),
// deferred l reduction. LDS 32 KB.
#define SEG(qt,a,b,s) ((unsigned)((qt)|((a)<<5)|((b)<<11)|((s)<<18)))
__constant__ unsigned SEGTAB[128] = {
  SEG(0,0,2,127),   SEG(15,0,15,14),
  SEG(15,15,32,15), 0,
  SEG(1,0,4,127),   SEG(14,0,13,12),
  SEG(14,13,30,13), 0,
  SEG(2,0,6,127),   SEG(13,0,11,10),
  SEG(13,11,28,11), 0,
  SEG(3,0,8,127),   SEG(12,0,9,8),
  SEG(12,9,26,9),   0,
  SEG(4,0,10,127),  SEG(11,0,7,6),
  SEG(11,7,24,7),   0,
  SEG(5,0,12,127),  SEG(10,0,5,4),
  SEG(10,5,22,5),   0,
  SEG(6,0,14,127),  SEG(9,0,3,2),
  SEG(9,3,20,3),    0,
  SEG(7,0,16,127),  SEG(8,0,1,0),
  SEG(8,1,18,1),    0,
  SEG(16,0,16,16),  0,
  SEG(16,16,33,17), 0,
  SEG(16,33,34,18), SEG(17,0,15,19),
  SEG(17,15,31,20), 0,
  SEG(17,31,36,21), SEG(18,0,12,22),
  SEG(18,12,28,23), 0,
  SEG(18,28,38,24), SEG(19,0,6,25),
  SEG(19,6,23,26),  0,
  SEG(19,23,39,27), 0,
  SEG(19,39,40,28), SEG(20,0,15,29),
  SEG(20,15,32,30), 0,
  SEG(20,32,42,31), SEG(21,0,6,32),
  SEG(21,6,22,33),  0,
  SEG(21,22,39,34), 0,
  SEG(21,39,44,35), SEG(22,0,11,36),
  SEG(22,11,27,37), 0,
  SEG(22,27,44,38), 0,
  SEG(22,44,46,39), SEG(23,0,14,40),
  SEG(23,14,30,41), 0,
  SEG(23,30,47,42), 0,
  SEG(23,47,48,43), SEG(24,0,15,44),
  SEG(24,15,31,45), 0,
  SEG(24,31,48,46), 0,
  SEG(24,48,50,47), SEG(25,0,14,48),
  SEG(25,14,30,49), 0,
  SEG(25,30,47,50), 0,
  SEG(25,47,52,51), SEG(26,0,11,52),
  SEG(26,11,27,53), 0,
  SEG(26,27,44,54), 0,
  SEG(26,44,54,55), SEG(27,0,6,56),
  SEG(27,6,22,57),  0,
  SEG(27,22,39,58), 0,
  SEG(27,39,55,59), 0,
  SEG(27,55,56,60), SEG(28,0,15,61),
  SEG(28,15,32,62), 0,
  SEG(28,32,48,63), 0,
  SEG(28,48,58,64), SEG(29,0,6,65),
  SEG(29,6,23,66),  0,
  SEG(29,23,39,67), 0,
  SEG(29,39,55,68), 0,
  SEG(29,55,60,69), SEG(30,0,12,70),
  SEG(30,12,28,71), 0,
  SEG(30,28,44,72), 0,
  SEG(30,44,61,73), 0,
  SEG(30,61,62,74), SEG(31,0,15,75),
  SEG(31,15,31,76), 0,
  SEG(31,31,48,77), 0,
  SEG(31,48,64,78), 0,
};
__constant__ unsigned char CBASE[24] = {0,2,4,6,8,10,12,14, 16,19,22,25,29,32,36,40, 44,48,52,56,61,65,70,75};
__constant__ unsigned char CCNT[24]  = {2,2,2,2,2,2,2,2, 3,3,3,4,3,4,4,4, 4,4,4,5,4,5,5,4};

__global__ __launch_bounds__(256, 4) void attn(const u16* __restrict__ Q,
                                               const u16* __restrict__ Kh,
                                               const u16* __restrict__ Vt,
                                               u16* __restrict__ Y,
                                               u16* __restrict__ Opart,
                                               float* __restrict__ MLpart) {
  const int tid = threadIdx.x, lane = tid & 63, wid = tid >> 6;
  const int lr = lane & 15, lq = lane >> 4;
  const int b = blockIdx.x;
  const int h = b & 15, unit = b >> 4;
  const int kvh = h >> 2;

  __shared__ u16 sK[4 * 64 * 32];   // [kc][kr][32]
  __shared__ u16 sVt[128 * 64];     // [d][kv' xor-swizzled]

  const u16* Kbase = Kh + (size_t)kvh * 64 * 8192;
  const u16* Vbase = Vt + (size_t)kvh * 64 * 8192;

  const int o01 = (((2 * lq) ^ (lr & 7)) << 3);
  const int o23 = (((2 * lq + 1) ^ (lr & 7)) << 3);

  #pragma unroll 1
  for (int si = 0; si < 2; ++si) {
    const unsigned sd = SEGTAB[unit * 2 + si];
    const int qt = sd & 31;
    const int t0 = (sd >> 5) & 63;
    const int t1 = (sd >> 11) & 127;
    const int slot = (sd >> 18) & 127;
    if (t1 <= t0) continue;
    const int qbase = qt * 128;

    s16x8 qf[2][4];
    #pragma unroll
    for (int f = 0; f < 2; f++) {
      const u16* qp = Q + ((size_t)h * 4096 + qbase + wid * 32 + f * 16 + lr) * 128 + lq * 8;
      #pragma unroll
      for (int kc = 0; kc < 4; kc++) qf[f][kc] = *(const s16x8*)(qp + kc * 32);
    }

    f32x4 oacc[2][8] = {};
    f32x4 lacc[2] = {};
    float mrow[2] = {-1e30f, -1e30f};

    for (int t = t0; t < t1; ++t) {
      const u16* Kt = Kbase + (size_t)t * 8192;
      const u16* Vtt = Vbase + (size_t)t * 8192;
      #pragma unroll
      for (int it = 0; it < 4; it++) {
        int off = it * 2048 + tid * 8;
        async16(Kt + off, &sK[off]);
        async16(Vtt + off, &sVt[off]);
      }
      __syncthreads();

      // S^T = K · Q^T
      f32x4 sacc[2][4] = {};
      #pragma unroll
      for (int nt = 0; nt < 4; nt++)
        #pragma unroll
        for (int kc = 0; kc < 4; kc++) {
          s16x8 kf = *(const s16x8*)&sK[kc * 2048 + (nt * 16 + lr) * 32 + lq * 8];
          sacc[0][nt] = __builtin_amdgcn_mfma_f32_16x16x32_bf16(kf, qf[0][kc], sacc[0][nt], 0, 0, 0);
          sacc[1][nt] = __builtin_amdgcn_mfma_f32_16x16x32_bf16(kf, qf[1][kc], sacc[1][nt], 0, 0, 0);
        }

      if (t >= 2 * qt) {   // causal mask: kv > q
        #pragma unroll
        for (int f = 0; f < 2; f++) {
          int qg = qbase + wid * 32 + f * 16 + lr;
          #pragma unroll
          for (int nt = 0; nt < 4; nt++) {
            int kv0 = t * 64 + nt * 16 + lq * 4;
            #pragma unroll
            for (int r = 0; r < 4; r++)
              if (kv0 + r > qg) sacc[f][nt][r] = -1e30f;
          }
        }
      }

      // per-lane max (no shuffles); trigger rescale only past stale-max margin
      float pm[2];
      #pragma unroll
      for (int f = 0; f < 2; f++) {
        float a = fmaxf(fmaxf(sacc[f][0][0], sacc[f][0][1]), fmaxf(sacc[f][0][2], sacc[f][0][3]));
        float bb = fmaxf(fmaxf(sacc[f][1][0], sacc[f][1][1]), fmaxf(sacc[f][1][2], sacc[f][1][3]));
        float cc = fmaxf(fmaxf(sacc[f][2][0], sacc[f][2][1]), fmaxf(sacc[f][2][2], sacc[f][2][3]));
        float dd = fmaxf(fmaxf(sacc[f][3][0], sacc[f][3][1]), fmaxf(sacc[f][3][2], sacc[f][3][3]));
        pm[f] = fmaxf(fmaxf(a, bb), fmaxf(cc, dd));
      }
      if (__any((pm[0] > mrow[0] + 3.0f) || (pm[1] > mrow[1] + 3.0f))) {
        #pragma unroll
        for (int f = 0; f < 2; f++) {
          float mn = pm[f];
          mn = fmaxf(mn, __shfl_xor(mn, 16, 64));
          mn = fmaxf(mn, __shfl_xor(mn, 32, 64));
          mn = fmaxf(mn, mrow[f]);
          float al = exp2f(mrow[f] - mn);
          mrow[f] = mn;
          lacc[f] *= al;
          #pragma unroll
          for (int dt = 0; dt < 8; dt++)
            #pragma unroll
            for (int r = 0; r < 4; r++) oacc[f][dt][r] *= al;
        }
      }

      // P^T = exp2(S^T - m): pack bf16 (trunc), accumulate per-lane l
      s16x4 pf[2][4];
      #pragma unroll
      for (int f = 0; f < 2; f++)
        #pragma unroll
        for (int nt = 0; nt < 4; nt++)
          #pragma unroll
          for (int r = 0; r < 4; r++) {
            union { float fv; unsigned u; } pu;
            pu.fv = exp2f(sacc[f][nt][r] - mrow[f]);
            lacc[f][r] += pu.fv;
            pf[f][nt][r] = (short)(pu.u >> 16);
          }

      // O^T += V^T · P^T  (16x16x16)
      #pragma unroll
      for (int dt = 0; dt < 8; dt++) {
        const u16* vrow = &sVt[(dt * 16 + lr) * 64];
        s16x8 v01 = *(const s16x8*)(vrow + o01);
        s16x8 v23 = *(const s16x8*)(vrow + o23);
        s16x4 vf0 = {v01[0], v01[1], v01[2], v01[3]};
        s16x4 vf1 = {v01[4], v01[5], v01[6], v01[7]};
        s16x4 vf2 = {v23[0], v23[1], v23[2], v23[3]};
        s16x4 vf3 = {v23[4], v23[5], v23[6], v23[7]};
        #pragma unroll
        for (int f = 0; f < 2; f++) {
          oacc[f][dt] = __builtin_amdgcn_mfma_f32_16x16x16bf16_1k(vf0, pf[f][0], oacc[f][dt], 0, 0, 0);
          oacc[f][dt] = __builtin_amdgcn_mfma_f32_16x16x16bf16_1k(vf1, pf[f][1], oacc[f][dt], 0, 0, 0);
          oacc[f][dt] = __builtin_amdgcn_mfma_f32_16x16x16bf16_1k(vf2, pf[f][2], oacc[f][dt], 0, 0, 0);
          oacc[f][dt] = __builtin_amdgcn_mfma_f32_16x16x16bf16_1k(vf3, pf[f][3], oacc[f][dt], 0, 0, 0);
        }
      }
      __syncthreads();
    }

    // final l: reduce regs then cross-lane (once per segment)
    float lrow[2];
    #pragma unroll
    for (int f = 0; f < 2; f++) {
      float s4 = (lacc[f][0] + lacc[f][1]) + (lacc[f][2] + lacc[f][3]);
      s4 += __shfl_xor(s4, 16, 64);
      s4 += __shfl_xor(s4, 32, 64);
      lrow[f] = s4;
    }

    // epilogue: lane layout q = wid*32 + f*16 + lr, d = dt*16 + lq*4 + r
    if (slot == 127) {
      #pragma unroll
      for (int f = 0; f < 2; f++) {
        float linv = 1.0f / lrow[f];
        int qg = qbase + wid * 32 + f * 16 + lr;
        #pragma unroll
        for (int dt = 0; dt < 8; dt++) {
          u16 tmp[4];
          #pragma unroll
          for (int r = 0; r < 4; r++) tmp[r] = f2bf(oacc[f][dt][r] * linv);
          *(s16x4*)&Y[(size_t)qg * 2048 + h * 128 + dt * 16 + lq * 4] = *(s16x4*)tmp;
        }
      }
    } else {
      const int gslot = h * 79 + slot;
      u16* Op = Opart + (size_t)gslot * 16384;
      #pragma unroll
      for (int f = 0; f < 2; f++) {
        int row = wid * 32 + f * 16 + lr;
        #pragma unroll
        for (int dt = 0; dt < 8; dt++) {
          u16 tmp[4];
          #pragma unroll
          for (int r = 0; r < 4; r++) tmp[r] = f2bf(oacc[f][dt][r]);
          *(s16x4*)&Op[row * 128 + dt * 16 + lq * 4] = *(s16x4*)tmp;
        }
        if (lq == 0) {
          MLpart[(size_t)gslot * 256 + row * 2]     = mrow[f];
          MLpart[(size_t)gslot * 256 + row * 2 + 1] = lrow[f];
        }
      }
    }
  }
}

// ---------------- combine: merge 2-5 partials per split tile -> Y ----------
__global__ __launch_bounds__(256) void combine(const u16* __restrict__ Op,
                                               const float* __restrict__ ML,
                                               u16* __restrict__ Y) {
  const int b = blockIdx.x;
  const int qt = 8 + (b >> 4), h = b & 15;
  const int base = CBASE[qt - 8], n = CCNT[qt - 8];
  const int gbase = h * 79 + base;
  const int tid = threadIdx.x;
  const int row = tid >> 1, half = (tid & 1) * 64;

  float m[5], l[5];
  float mstar = -3e38f;
  for (int i = 0; i < n; i++) {
    m[i] = ML[(size_t)(gbase + i) * 256 + row * 2];
    l[i] = ML[(size_t)(gbase + i) * 256 + row * 2 + 1];
    mstar = fmaxf(mstar, m[i]);
  }
  float w[5], wsum = 0.f;
  for (int i = 0; i < n; i++) { w[i] = exp2f(m[i] - mstar); wsum += l[i] * w[i]; }
  float inv = 1.0f / wsum;

  float acc[64] = {};
  for (int i = 0; i < n; i++) {
    const u16* o = Op + (size_t)(gbase + i) * 16384 + row * 128 + half;
    float wi = w[i];
    #pragma unroll
    for (int c = 0; c < 64; c += 8) {
      s16x8 a = *(const s16x8*)(o + c);
      #pragma unroll
      for (int jj = 0; jj < 8; jj++) acc[c + jj] += wi * bf2f((u16)a[jj]);
    }
  }
  u16* dst = Y + ((size_t)qt * 128 + row) * 2048 + h * 128 + half;
  #pragma unroll
  for (int c = 0; c < 64; c += 8) {
    u16 tmp[8];
    #pragma unroll
    for (int jj = 0; jj < 8; jj++) tmp[jj] = f2bf(acc[c + jj] * inv);
    *(s16x8*)(dst + c) = *(s16x8*)tmp;
  }
}

// ---------------- launch ----------------
extern "C" void kernel_launch(void* const* d_in, const int* in_sizes, int n_in,
                              void* d_out, int out_size, void* d_ws, size_t ws_size,
                              hipStream_t stream) {
  const float* x  = (const float*)d_in[0];
  const float* wq = (const float*)d_in[1];
  const float* wk = (const float*)d_in[2];
  const float* wv = (const float*)d_in[3];
  const float* wp = (const float*)d_in[4];
  const float* qg = (const float*)d_in[5];
  float* out = (float*)d_out;
  char* ws = (char*)d_ws;

  u16*   XB    = (u16*)(ws + OFF_XB);
  u16*   WQKV  = (u16*)(ws + OFF_WQKV);
  u16*   WP    = (u16*)(ws + OFF_WP);
  float* QKV   = (float*)(ws + OFF_QKV);
  u16*   QH    = XB;                      // reuse after GEMM1
  u16*   KH    = (u16*)(ws + OFF_KH);     // reuse of WQKV region after GEMM1
  u16*   VT    = (u16*)(ws + OFF_VT);
  float* MLP   = (float*)(ws + OFF_ML);
  u16*   OPART = (u16*)(ws + OFF_QKV);    // reuse after prep/vtrans
  u16*   Yb    = (u16*)(ws + OFF_Y);

  quant_all<<<5120, 256, 0, stream>>>(wq, wk, wv, wp, WQKV, WP);
  cvt_bf16<<<8192, 256, 0, stream>>>(x, XB);
  gemm_bt<<<dim3(24, 32), 256, 0, stream>>>(XB, WQKV, QKV, 4096, 3072, 2048);
  prep_qk<<<dim3(5, 4096), 256, 0, stream>>>(QKV, qg, QH, KH);
  vtrans<<<dim3(8, 64), 256, 0, stream>>>(QKV, VT);
  attn<<<1024, 256, 0, stream>>>(QH, KH, VT, Yb, OPART, MLP);
  combine<<<384, 256, 0, stream>>>(OPART, MLP, Yb);
  gemm_bt<<<dim3(16, 32), 256, 0, stream>>>(Yb, WP, out, 4096, 2048, 2048);
}

// Round 7
// 391.213 us; speedup vs baseline: 1.6079x; 1.6079x over previous
//
#include <hip/hip_runtime.h>
#include <math.h>

typedef unsigned short u16;
typedef short s16x8 __attribute__((ext_vector_type(8)));
typedef short s16x4 __attribute__((ext_vector_type(4)));
typedef float f32x4 __attribute__((ext_vector_type(4)));
typedef u16 u16x4 __attribute__((ext_vector_type(4)));

// ---------------- workspace layout (bytes) ----------------
// XB   : x bf16 [4096][2048]               16,777,216  (reused as QH [16][4096][128])
// WQKV : qkv weights bf16 [3072][2048]     12,582,912  (region reused after gemm1:
//          KH bf16 [4][64][4][64][32] @ +0 (4 MB)  -- K tiled [t][kc][kr][c]
//          VT bf16 [4][64][128][64] @ +4,194,304 (4 MB) -- V^T tiled, permuted+xor-swizzled
//          ML f32 [16*79][128][2]  @ +8,388,608 (1,294,336 B))
// WP   : proj weights bf16 [2048][2048]     8,388,608
// QKV  : fp32 [4096][3072]                 50,331,648  (reused: Opart bf16 1264x[128][128] = 41,418,752)
// Y    : bf16 [4096][2048] @ 79,691,776    16,777,216
static constexpr size_t OFF_XB   = 0;
static constexpr size_t OFF_WQKV = 16777216;
static constexpr size_t OFF_KH   = 16777216;
static constexpr size_t OFF_VT   = 20971520;
static constexpr size_t OFF_ML   = 25165824;
static constexpr size_t OFF_WP   = 29360128;
static constexpr size_t OFF_QKV  = 37748736;
static constexpr size_t OFF_Y    = 79691776;

__device__ __forceinline__ u16 f2bf(float f) {
  union { float f; unsigned u; } v; v.f = f;
  unsigned r = v.u + 0x7fffu + ((v.u >> 16) & 1u);   // RNE
  return (u16)(r >> 16);
}

__device__ __forceinline__ float bf2f(u16 b) {
  union { unsigned u; float f; } v; v.u = ((unsigned)b) << 16;
  return v.f;
}

__device__ __forceinline__ void async16(const u16* g, u16* lds) {
  __builtin_amdgcn_global_load_lds(
      (const __attribute__((address_space(1))) void*)g,
      (__attribute__((address_space(3))) void*)lds, 16, 0, 0);
}

// ---------------- bitlinear weight quantization (fused, 5120 rows) ----------
__global__ __launch_bounds__(256) void quant_all(const float* __restrict__ wq,
                                                 const float* __restrict__ wk,
                                                 const float* __restrict__ wv,
                                                 const float* __restrict__ wp,
                                                 u16* __restrict__ outqkv,
                                                 u16* __restrict__ outp) {
  const int row = blockIdx.x, tid = threadIdx.x;
  const float* src;
  u16* dst;
  if (row < 2048)      { src = wq + (size_t)row * 2048;          dst = outqkv + (size_t)row * 2048; }
  else if (row < 2560) { src = wk + (size_t)(row - 2048) * 2048; dst = outqkv + (size_t)row * 2048; }
  else if (row < 3072) { src = wv + (size_t)(row - 2560) * 2048; dst = outqkv + (size_t)row * 2048; }
  else                 { src = wp + (size_t)(row - 3072) * 2048; dst = outp + (size_t)(row - 3072) * 2048; }
  src += tid * 8;
  float4 a = *(const float4*)(src);
  float4 b = *(const float4*)(src + 4);
  float asum = fabsf(a.x)+fabsf(a.y)+fabsf(a.z)+fabsf(a.w)
             + fabsf(b.x)+fabsf(b.y)+fabsf(b.z)+fabsf(b.w);
  #pragma unroll
  for (int off = 1; off < 64; off <<= 1) asum += __shfl_xor(asum, off, 64);
  __shared__ float red[4];
  if ((tid & 63) == 0) red[tid >> 6] = asum;
  __syncthreads();
  float s = fmaxf((red[0]+red[1]+red[2]+red[3]) * (1.0f/2048.0f), 1e-5f);
  float v[8] = {a.x,a.y,a.z,a.w,b.x,b.y,b.z,b.w};
  u16* d = dst + tid * 8;
  #pragma unroll
  for (int i = 0; i < 8; i++) {
    float q = rintf(v[i] / s);
    q = fminf(fmaxf(q, -1.f), 1.f);
    d[i] = f2bf(q * s);
  }
}

// ---------------- fp32 -> bf16 ----------------
__global__ __launch_bounds__(256) void cvt_bf16(const float* __restrict__ in,
                                                u16* __restrict__ out) {
  size_t i = ((size_t)blockIdx.x * 256 + threadIdx.x) * 4;
  float4 v = *(const float4*)(in + i);
  u16x4 o;
  o.x = f2bf(v.x); o.y = f2bf(v.y); o.z = f2bf(v.z); o.w = f2bf(v.w);
  *(u16x4*)(out + i) = o;
}

// ---------------- GEMM  C[M][N] = A[M][K] * B[N][K]^T  (bf16 in, fp32 out) -------
__global__ __launch_bounds__(256) void gemm_bt(const u16* __restrict__ A,
                                               const u16* __restrict__ B,
                                               float* __restrict__ C,
                                               int M, int N, int K) {
  __shared__ u16 sA[128 * 32];
  __shared__ u16 sB[128 * 32];
  const int tid = threadIdx.x;
  const int lane = tid & 63;
  const int wid = tid >> 6;
  const int lr = lane & 15, lq = lane >> 4;
  const int wm = (wid >> 1) * 64, wn = (wid & 1) * 64;
  const size_t m0 = (size_t)blockIdx.y * 128, n0 = (size_t)blockIdx.x * 128;

  const int r0 = tid >> 2, c0 = (tid & 3) * 8;
  const u16* Ab0 = A + (m0 + r0) * (size_t)K + c0;
  const u16* Ab1 = A + (m0 + 64 + r0) * (size_t)K + c0;
  const u16* Bb0 = B + (n0 + r0) * (size_t)K + c0;
  const u16* Bb1 = B + (n0 + 64 + r0) * (size_t)K + c0;
  u16* sA0 = &sA[tid * 8];
  u16* sA1 = &sA[(256 + tid) * 8];
  u16* sB0 = &sB[tid * 8];
  u16* sB1 = &sB[(256 + tid) * 8];

  f32x4 acc[4][4] = {};

  for (int kt = 0; kt < K; kt += 32) {
    async16(Ab0 + kt, sA0);
    async16(Ab1 + kt, sA1);
    async16(Bb0 + kt, sB0);
    async16(Bb1 + kt, sB1);
    __syncthreads();
    s16x8 af[4], bf[4];
    #pragma unroll
    for (int mt = 0; mt < 4; mt++)
      af[mt] = *(const s16x8*)&sA[(wm + mt * 16 + lr) * 32 + lq * 8];
    #pragma unroll
    for (int nt = 0; nt < 4; nt++)
      bf[nt] = *(const s16x8*)&sB[(wn + nt * 16 + lr) * 32 + lq * 8];
    #pragma unroll
    for (int mt = 0; mt < 4; mt++)
      #pragma unroll
      for (int nt = 0; nt < 4; nt++)
        acc[mt][nt] = __builtin_amdgcn_mfma_f32_16x16x32_bf16(af[mt], bf[nt], acc[mt][nt], 0, 0, 0);
    __syncthreads();
  }
  #pragma unroll
  for (int mt = 0; mt < 4; mt++)
    #pragma unroll
    for (int nt = 0; nt < 4; nt++)
      #pragma unroll
      for (int r = 0; r < 4; r++) {
        size_t m = m0 + wm + mt * 16 + lq * 4 + r;
        size_t n = n0 + wn + nt * 16 + lr;
        C[m * (size_t)N + n] = acc[mt][nt][r];
      }
}

// ---------------- rmsnorm + rope; K written in attn-staging layout ----------
__global__ __launch_bounds__(256) void prep_qk(const float* __restrict__ qkv,
                                               const float* __restrict__ qgain,
                                               u16* __restrict__ Qh,
                                               u16* __restrict__ Kh) {
  const int s = blockIdx.y;
  const int j = blockIdx.x * 4 + (threadIdx.x >> 6);
  const int t = threadIdx.x & 63;
  const float* row = qkv + (size_t)s * 3072 + (size_t)j * 128;
  float x1 = row[t], x2 = row[t + 64];
  float ss = x1 * x1 + x2 * x2;
  #pragma unroll
  for (int off = 1; off < 64; off <<= 1) ss += __shfl_xor(ss, off, 64);
  float rn = rsqrtf(ss * (1.0f / 128.0f) + 1.1920929e-07f);
  float invf = exp2f(-(float)t * 0.20762050593048096f);  // log2(10000)/64
  float ang = (float)s * invf;
  float sn, c;
  sincosf(ang, &sn, &c);
  if (j < 16) {
    float g = qgain[j] * 0.12751738f;   // (1/sqrt(128)) * log2(e)
    float q1 = x1 * rn, q2 = x2 * rn;
    float o1 = (q1 * c + q2 * sn) * g;
    float o2 = (-q1 * sn + q2 * c) * g;
    u16* dst = Qh + ((size_t)j * 4096 + s) * 128;
    dst[t] = f2bf(o1); dst[t + 64] = f2bf(o2);
  } else {
    const int kvh = j - 16;
    float k1 = x1 * rn, k2 = x2 * rn;
    float o1 = k1 * c + k2 * sn;
    float o2 = -k1 * sn + k2 * c;
    // KH[kvh][tt][kc][kr][c32]: d=t -> kc=t>>5, d=t+64 -> kc=2+(t>>5)
    const int tt = s >> 6, kr = s & 63;
    u16* base = Kh + (((size_t)kvh * 64 + tt) * 4) * 2048 + kr * 32 + (t & 31);
    base[(size_t)(t >> 5) * 2048]       = f2bf(o1);
    base[(size_t)(2 + (t >> 5)) * 2048] = f2bf(o2);
  }
}

// ---------------- V transpose into attn-staging layout ----------------------
// VT[kvh][tt][d][64]: per (d, kv-tile) row of 64, kv permuted
// kv' = 16*((kv>>2)&3) + 4*(kv>>4) + (kv&3), then 16B-granules XORed by (d&7).
__global__ __launch_bounds__(256) void vtrans(const float* __restrict__ qkv,
                                              u16* __restrict__ Vtg) {
  __shared__ float tile[64][67];
  const int tid = threadIdx.x;
  const int s0 = blockIdx.y * 64;
  const int c0 = blockIdx.x * 64;
  #pragma unroll
  for (int it = 0; it < 4; it++) {
    int i = it * 256 + tid;
    int r = i >> 4, c = (i & 15) * 4;
    float4 v = *(const float4*)(qkv + (size_t)(s0 + r) * 3072 + 2560 + c0 + c);
    tile[r][c] = v.x; tile[r][c + 1] = v.y; tile[r][c + 2] = v.z; tile[r][c + 3] = v.w;
  }
  __syncthreads();
  #pragma unroll
  for (int it = 0; it < 2; it++) {
    int i = it * 256 + tid;
    int dl = i >> 3, sc = (i & 7) * 8;
    int cglob = c0 + dl;
    int kvh = cglob >> 7, d = cglob & 127;
    int tt = s0 >> 6;
    int a0 = 16 * ((sc >> 2) & 3) + 4 * (sc >> 4);
    int a1 = 16 * (((sc >> 2) + 1) & 3) + 4 * (sc >> 4);
    int x = d & 7;
    int p0 = ((((a0 >> 3) ^ x) << 3) | (a0 & 7));
    int p1 = ((((a1 >> 3) ^ x) << 3) | (a1 & 7));
    size_t rowbase = (((size_t)kvh * 64 + tt) * 128 + d) * 64;
    u16 lo[4], hi[4];
    #pragma unroll
    for (int jj = 0; jj < 4; jj++) lo[jj] = f2bf(tile[sc + jj][dl]);
    #pragma unroll
    for (int jj = 0; jj < 4; jj++) hi[jj] = f2bf(tile[sc + 4 + jj][dl]);
    *(s16x4*)&Vtg[rowbase + p0] = *(s16x4*)lo;
    *(s16x4*)&Vtg[rowbase + p1] = *(s16x4*)hi;
  }
}

// ---------------- flash attention v7 (v6 structure, spill-free regs) --------
// Uniform 16/17-step units, S^T form, P in registers, global_load_lds staging
// from pre-arranged K/V layouts, stale-max (margin 3), deferred l reduction.
// __launch_bounds__(256, 2): 256-VGPR cap -- compiler picks ~116, NO spill.
// (256,4) forced 64 VGPRs and spilled accumulators to scratch: 776 MB FETCH,
// 745 MB WRITE, 2.4x regression. Never cap below live-state size.
#define SEG(qt,a,b,s) ((unsigned)((qt)|((a)<<5)|((b)<<11)|((s)<<18)))
__constant__ unsigned SEGTAB[128] = {
  SEG(0,0,2,127),   SEG(15,0,15,14),
  SEG(15,15,32,15), 0,
  SEG(1,0,4,127),   SEG(14,0,13,12),
  SEG(14,13,30,13), 0,
  SEG(2,0,6,127),   SEG(13,0,11,10),
  SEG(13,11,28,11), 0,
  SEG(3,0,8,127),   SEG(12,0,9,8),
  SEG(12,9,26,9),   0,
  SEG(4,0,10,127),  SEG(11,0,7,6),
  SEG(11,7,24,7),   0,
  SEG(5,0,12,127),  SEG(10,0,5,4),
  SEG(10,5,22,5),   0,
  SEG(6,0,14,127),  SEG(9,0,3,2),
  SEG(9,3,20,3),    0,
  SEG(7,0,16,127),  SEG(8,0,1,0),
  SEG(8,1,18,1),    0,
  SEG(16,0,16,16),  0,
  SEG(16,16,33,17), 0,
  SEG(16,33,34,18), SEG(17,0,15,19),
  SEG(17,15,31,20), 0,
  SEG(17,31,36,21), SEG(18,0,12,22),
  SEG(18,12,28,23), 0,
  SEG(18,28,38,24), SEG(19,0,6,25),
  SEG(19,6,23,26),  0,
  SEG(19,23,39,27), 0,
  SEG(19,39,40,28), SEG(20,0,15,29),
  SEG(20,15,32,30), 0,
  SEG(20,32,42,31), SEG(21,0,6,32),
  SEG(21,6,22,33),  0,
  SEG(21,22,39,34), 0,
  SEG(21,39,44,35), SEG(22,0,11,36),
  SEG(22,11,27,37), 0,
  SEG(22,27,44,38), 0,
  SEG(22,44,46,39), SEG(23,0,14,40),
  SEG(23,14,30,41), 0,
  SEG(23,30,47,42), 0,
  SEG(23,47,48,43), SEG(24,0,15,44),
  SEG(24,15,31,45), 0,
  SEG(24,31,48,46), 0,
  SEG(24,48,50,47), SEG(25,0,14,48),
  SEG(25,14,30,49), 0,
  SEG(25,30,47,50), 0,
  SEG(25,47,52,51), SEG(26,0,11,52),
  SEG(26,11,27,53), 0,
  SEG(26,27,44,54), 0,
  SEG(26,44,54,55), SEG(27,0,6,56),
  SEG(27,6,22,57),  0,
  SEG(27,22,39,58), 0,
  SEG(27,39,55,59), 0,
  SEG(27,55,56,60), SEG(28,0,15,61),
  SEG(28,15,32,62), 0,
  SEG(28,32,48,63), 0,
  SEG(28,48,58,64), SEG(29,0,6,65),
  SEG(29,6,23,66),  0,
  SEG(29,23,39,67), 0,
  SEG(29,39,55,68), 0,
  SEG(29,55,60,69), SEG(30,0,12,70),
  SEG(30,12,28,71), 0,
  SEG(30,28,44,72), 0,
  SEG(30,44,61,73), 0,
  SEG(30,61,62,74), SEG(31,0,15,75),
  SEG(31,15,31,76), 0,
  SEG(31,31,48,77), 0,
  SEG(31,48,64,78), 0,
};
__constant__ unsigned char CBASE[24] = {0,2,4,6,8,10,12,14, 16,19,22,25,29,32,36,40, 44,48,52,56,61,65,70,75};
__constant__ unsigned char CCNT[24]  = {2,2,2,2,2,2,2,2, 3,3,3,4,3,4,4,4, 4,4,4,5,4,5,5,4};

__global__ __launch_bounds__(256, 2) void attn(const u16* __restrict__ Q,
                                               const u16* __restrict__ Kh,
                                               const u16* __restrict__ Vt,
                                               u16* __restrict__ Y,
                                               u16* __restrict__ Opart,
                                               float* __restrict__ MLpart) {
  const int tid = threadIdx.x, lane = tid & 63, wid = tid >> 6;
  const int lr = lane & 15, lq = lane >> 4;
  const int b = blockIdx.x;
  const int h = b & 15, unit = b >> 4;
  const int kvh = h >> 2;

  __shared__ u16 sK[4 * 64 * 32];   // [kc][kr][32]
  __shared__ u16 sVt[128 * 64];     // [d][kv' xor-swizzled]

  const u16* Kbase = Kh + (size_t)kvh * 64 * 8192;
  const u16* Vbase = Vt + (size_t)kvh * 64 * 8192;

  const int o01 = (((2 * lq) ^ (lr & 7)) << 3);
  const int o23 = (((2 * lq + 1) ^ (lr & 7)) << 3);

  #pragma unroll 1
  for (int si = 0; si < 2; ++si) {
    const unsigned sd = SEGTAB[unit * 2 + si];
    const int qt = sd & 31;
    const int t0 = (sd >> 5) & 63;
    const int t1 = (sd >> 11) & 127;
    const int slot = (sd >> 18) & 127;
    if (t1 <= t0) continue;
    const int qbase = qt * 128;

    s16x8 qf[2][4];
    #pragma unroll
    for (int f = 0; f < 2; f++) {
      const u16* qp = Q + ((size_t)h * 4096 + qbase + wid * 32 + f * 16 + lr) * 128 + lq * 8;
      #pragma unroll
      for (int kc = 0; kc < 4; kc++) qf[f][kc] = *(const s16x8*)(qp + kc * 32);
    }

    f32x4 oacc[2][8] = {};
    f32x4 lacc[2] = {};
    float mrow[2] = {-1e30f, -1e30f};

    for (int t = t0; t < t1; ++t) {
      const u16* Kt = Kbase + (size_t)t * 8192;
      const u16* Vtt = Vbase + (size_t)t * 8192;
      #pragma unroll
      for (int it = 0; it < 4; it++) {
        int off = it * 2048 + tid * 8;
        async16(Kt + off, &sK[off]);
        async16(Vtt + off, &sVt[off]);
      }
      __syncthreads();

      // S^T = K · Q^T
      f32x4 sacc[2][4] = {};
      #pragma unroll
      for (int nt = 0; nt < 4; nt++)
        #pragma unroll
        for (int kc = 0; kc < 4; kc++) {
          s16x8 kf = *(const s16x8*)&sK[kc * 2048 + (nt * 16 + lr) * 32 + lq * 8];
          sacc[0][nt] = __builtin_amdgcn_mfma_f32_16x16x32_bf16(kf, qf[0][kc], sacc[0][nt], 0, 0, 0);
          sacc[1][nt] = __builtin_amdgcn_mfma_f32_16x16x32_bf16(kf, qf[1][kc], sacc[1][nt], 0, 0, 0);
        }

      if (t >= 2 * qt) {   // causal mask: kv > q
        #pragma unroll
        for (int f = 0; f < 2; f++) {
          int qg = qbase + wid * 32 + f * 16 + lr;
          #pragma unroll
          for (int nt = 0; nt < 4; nt++) {
            int kv0 = t * 64 + nt * 16 + lq * 4;
            #pragma unroll
            for (int r = 0; r < 4; r++)
              if (kv0 + r > qg) sacc[f][nt][r] = -1e30f;
          }
        }
      }

      // per-lane max (no shuffles); trigger rescale only past stale-max margin
      float pm[2];
      #pragma unroll
      for (int f = 0; f < 2; f++) {
        float a = fmaxf(fmaxf(sacc[f][0][0], sacc[f][0][1]), fmaxf(sacc[f][0][2], sacc[f][0][3]));
        float bb = fmaxf(fmaxf(sacc[f][1][0], sacc[f][1][1]), fmaxf(sacc[f][1][2], sacc[f][1][3]));
        float cc = fmaxf(fmaxf(sacc[f][2][0], sacc[f][2][1]), fmaxf(sacc[f][2][2], sacc[f][2][3]));
        float dd = fmaxf(fmaxf(sacc[f][3][0], sacc[f][3][1]), fmaxf(sacc[f][3][2], sacc[f][3][3]));
        pm[f] = fmaxf(fmaxf(a, bb), fmaxf(cc, dd));
      }
      if (__any((pm[0] > mrow[0] + 3.0f) || (pm[1] > mrow[1] + 3.0f))) {
        #pragma unroll
        for (int f = 0; f < 2; f++) {
          float mn = pm[f];
          mn = fmaxf(mn, __shfl_xor(mn, 16, 64));
          mn = fmaxf(mn, __shfl_xor(mn, 32, 64));
          mn = fmaxf(mn, mrow[f]);
          float al = exp2f(mrow[f] - mn);
          mrow[f] = mn;
          lacc[f] *= al;
          #pragma unroll
          for (int dt = 0; dt < 8; dt++)
            #pragma unroll
            for (int r = 0; r < 4; r++) oacc[f][dt][r] *= al;
        }
      }

      // P^T = exp2(S^T - m): pack bf16 (trunc), accumulate per-lane l
      s16x4 pf[2][4];
      #pragma unroll
      for (int f = 0; f < 2; f++)
        #pragma unroll
        for (int nt = 0; nt < 4; nt++)
          #pragma unroll
          for (int r = 0; r < 4; r++) {
            union { float fv; unsigned u; } pu;
            pu.fv = exp2f(sacc[f][nt][r] - mrow[f]);
            lacc[f][r] += pu.fv;
            pf[f][nt][r] = (short)(pu.u >> 16);
          }

      // O^T += V^T · P^T  (16x16x16)
      #pragma unroll
      for (int dt = 0; dt < 8; dt++) {
        const u16* vrow = &sVt[(dt * 16 + lr) * 64];
        s16x8 v01 = *(const s16x8*)(vrow + o01);
        s16x8 v23 = *(const s16x8*)(vrow + o23);
        s16x4 vf0 = {v01[0], v01[1], v01[2], v01[3]};
        s16x4 vf1 = {v01[4], v01[5], v01[6], v01[7]};
        s16x4 vf2 = {v23[0], v23[1], v23[2], v23[3]};
        s16x4 vf3 = {v23[4], v23[5], v23[6], v23[7]};
        #pragma unroll
        for (int f = 0; f < 2; f++) {
          oacc[f][dt] = __builtin_amdgcn_mfma_f32_16x16x16bf16_1k(vf0, pf[f][0], oacc[f][dt], 0, 0, 0);
          oacc[f][dt] = __builtin_amdgcn_mfma_f32_16x16x16bf16_1k(vf1, pf[f][1], oacc[f][dt], 0, 0, 0);
          oacc[f][dt] = __builtin_amdgcn_mfma_f32_16x16x16bf16_1k(vf2, pf[f][2], oacc[f][dt], 0, 0, 0);
          oacc[f][dt] = __builtin_amdgcn_mfma_f32_16x16x16bf16_1k(vf3, pf[f][3], oacc[f][dt], 0, 0, 0);
        }
      }
      __syncthreads();
    }

    // final l: reduce regs then cross-lane (once per segment)
    float lrow[2];
    #pragma unroll
    for (int f = 0; f < 2; f++) {
      float s4 = (lacc[f][0] + lacc[f][1]) + (lacc[f][2] + lacc[f][3]);
      s4 += __shfl_xor(s4, 16, 64);
      s4 += __shfl_xor(s4, 32, 64);
      lrow[f] = s4;
    }

    // epilogue: lane layout q = wid*32 + f*16 + lr, d = dt*16 + lq*4 + r
    if (slot == 127) {
      #pragma unroll
      for (int f = 0; f < 2; f++) {
        float linv = 1.0f / lrow[f];
        int qg = qbase + wid * 32 + f * 16 + lr;
        #pragma unroll
        for (int dt = 0; dt < 8; dt++) {
          u16 tmp[4];
          #pragma unroll
          for (int r = 0; r < 4; r++) tmp[r] = f2bf(oacc[f][dt][r] * linv);
          *(s16x4*)&Y[(size_t)qg * 2048 + h * 128 + dt * 16 + lq * 4] = *(s16x4*)tmp;
        }
      }
    } else {
      const int gslot = h * 79 + slot;
      u16* Op = Opart + (size_t)gslot * 16384;
      #pragma unroll
      for (int f = 0; f < 2; f++) {
        int row = wid * 32 + f * 16 + lr;
        #pragma unroll
        for (int dt = 0; dt < 8; dt++) {
          u16 tmp[4];
          #pragma unroll
          for (int r = 0; r < 4; r++) tmp[r] = f2bf(oacc[f][dt][r]);
          *(s16x4*)&Op[row * 128 + dt * 16 + lq * 4] = *(s16x4*)tmp;
        }
        if (lq == 0) {
          MLpart[(size_t)gslot * 256 + row * 2]     = mrow[f];
          MLpart[(size_t)gslot * 256 + row * 2 + 1] = lrow[f];
        }
      }
    }
  }
}

// ---------------- combine: merge 2-5 partials per split tile -> Y ----------
__global__ __launch_bounds__(256) void combine(const u16* __restrict__ Op,
                                               const float* __restrict__ ML,
                                               u16* __restrict__ Y) {
  const int b = blockIdx.x;
  const int qt = 8 + (b >> 4), h = b & 15;
  const int base = CBASE[qt - 8], n = CCNT[qt - 8];
  const int gbase = h * 79 + base;
  const int tid = threadIdx.x;
  const int row = tid >> 1, half = (tid & 1) * 64;

  float m[5], l[5];
  float mstar = -3e38f;
  for (int i = 0; i < n; i++) {
    m[i] = ML[(size_t)(gbase + i) * 256 + row * 2];
    l[i] = ML[(size_t)(gbase + i) * 256 + row * 2 + 1];
    mstar = fmaxf(mstar, m[i]);
  }
  float w[5], wsum = 0.f;
  for (int i = 0; i < n; i++) { w[i] = exp2f(m[i] - mstar); wsum += l[i] * w[i]; }
  float inv = 1.0f / wsum;

  float acc[64] = {};
  for (int i = 0; i < n; i++) {
    const u16* o = Op + (size_t)(gbase + i) * 16384 + row * 128 + half;
    float wi = w[i];
    #pragma unroll
    for (int c = 0; c < 64; c += 8) {
      s16x8 a = *(const s16x8*)(o + c);
      #pragma unroll
      for (int jj = 0; jj < 8; jj++) acc[c + jj] += wi * bf2f((u16)a[jj]);
    }
  }
  u16* dst = Y + ((size_t)qt * 128 + row) * 2048 + h * 128 + half;
  #pragma unroll
  for (int c = 0; c < 64; c += 8) {
    u16 tmp[8];
    #pragma unroll
    for (int jj = 0; jj < 8; jj++) tmp[jj] = f2bf(acc[c + jj] * inv);
    *(s16x8*)(dst + c) = *(s16x8*)tmp;
  }
}

// ---------------- launch ----------------
extern "C" void kernel_launch(void* const* d_in, const int* in_sizes, int n_in,
                              void* d_out, int out_size, void* d_ws, size_t ws_size,
                              hipStream_t stream) {
  const float* x  = (const float*)d_in[0];
  const float* wq = (const float*)d_in[1];
  const float* wk = (const float*)d_in[2];
  const float* wv = (const float*)d_in[3];
  const float* wp = (const float*)d_in[4];
  const float* qg = (const float*)d_in[5];
  float* out = (float*)d_out;
  char* ws = (char*)d_ws;

  u16*   XB    = (u16*)(ws + OFF_XB);
  u16*   WQKV  = (u16*)(ws + OFF_WQKV);
  u16*   WP    = (u16*)(ws + OFF_WP);
  float* QKV   = (float*)(ws + OFF_QKV);
  u16*   QH    = XB;                      // reuse after GEMM1
  u16*   KH    = (u16*)(ws + OFF_KH);     // reuse of WQKV region after GEMM1
  u16*   VT    = (u16*)(ws + OFF_VT);
  float* MLP   = (float*)(ws + OFF_ML);
  u16*   OPART = (u16*)(ws + OFF_QKV);    // reuse after prep/vtrans
  u16*   Yb    = (u16*)(ws + OFF_Y);

  quant_all<<<5120, 256, 0, stream>>>(wq, wk, wv, wp, WQKV, WP);
  cvt_bf16<<<8192, 256, 0, stream>>>(x, XB);
  gemm_bt<<<dim3(24, 32), 256, 0, stream>>>(XB, WQKV, QKV, 4096, 3072, 2048);
  prep_qk<<<dim3(5, 4096), 256, 0, stream>>>(QKV, qg, QH, KH);
  vtrans<<<dim3(8, 64), 256, 0, stream>>>(QKV, VT);
  attn<<<1024, 256, 0, stream>>>(QH, KH, VT, Yb, OPART, MLP);
  combine<<<384, 256, 0, stream>>>(OPART, MLP, Yb);
  gemm_bt<<<dim3(16, 32), 256, 0, stream>>>(Yb, WP, out, 4096, 2048, 2048);
}

// Round 9
// 378.005 us; speedup vs baseline: 1.6640x; 1.0349x over previous
//
#include <hip/hip_runtime.h>
#include <math.h>

typedef unsigned short u16;
typedef short s16x8 __attribute__((ext_vector_type(8)));
typedef short s16x4 __attribute__((ext_vector_type(4)));
typedef float f32x4 __attribute__((ext_vector_type(4)));
typedef u16 u16x4 __attribute__((ext_vector_type(4)));

// ---------------- workspace layout (bytes) ----------------
static constexpr size_t OFF_XB   = 0;
static constexpr size_t OFF_WQKV = 16777216;
static constexpr size_t OFF_KH   = 16777216;
static constexpr size_t OFF_VT   = 20971520;
static constexpr size_t OFF_ML   = 25165824;
static constexpr size_t OFF_WP   = 29360128;
static constexpr size_t OFF_QKV  = 37748736;
static constexpr size_t OFF_Y    = 79691776;

__device__ __forceinline__ u16 f2bf(float f) {
  union { float f; unsigned u; } v; v.f = f;
  unsigned r = v.u + 0x7fffu + ((v.u >> 16) & 1u);   // RNE
  return (u16)(r >> 16);
}

__device__ __forceinline__ float bf2f(u16 b) {
  union { unsigned u; float f; } v; v.u = ((unsigned)b) << 16;
  return v.f;
}

__device__ __forceinline__ void async16(const u16* g, u16* lds) {
  __builtin_amdgcn_global_load_lds(
      (const __attribute__((address_space(1))) void*)g,
      (__attribute__((address_space(3))) void*)lds, 16, 0, 0);
}

// ---------------- bitlinear weight quantization (fused, 5120 rows) ----------
__global__ __launch_bounds__(256) void quant_all(const float* __restrict__ wq,
                                                 const float* __restrict__ wk,
                                                 const float* __restrict__ wv,
                                                 const float* __restrict__ wp,
                                                 u16* __restrict__ outqkv,
                                                 u16* __restrict__ outp) {
  const int row = blockIdx.x, tid = threadIdx.x;
  const float* src;
  u16* dst;
  if (row < 2048)      { src = wq + (size_t)row * 2048;          dst = outqkv + (size_t)row * 2048; }
  else if (row < 2560) { src = wk + (size_t)(row - 2048) * 2048; dst = outqkv + (size_t)row * 2048; }
  else if (row < 3072) { src = wv + (size_t)(row - 2560) * 2048; dst = outqkv + (size_t)row * 2048; }
  else                 { src = wp + (size_t)(row - 3072) * 2048; dst = outp + (size_t)(row - 3072) * 2048; }
  src += tid * 8;
  float4 a = *(const float4*)(src);
  float4 b = *(const float4*)(src + 4);
  float asum = fabsf(a.x)+fabsf(a.y)+fabsf(a.z)+fabsf(a.w)
             + fabsf(b.x)+fabsf(b.y)+fabsf(b.z)+fabsf(b.w);
  #pragma unroll
  for (int off = 1; off < 64; off <<= 1) asum += __shfl_xor(asum, off, 64);
  __shared__ float red[4];
  if ((tid & 63) == 0) red[tid >> 6] = asum;
  __syncthreads();
  float s = fmaxf((red[0]+red[1]+red[2]+red[3]) * (1.0f/2048.0f), 1e-5f);
  float v[8] = {a.x,a.y,a.z,a.w,b.x,b.y,b.z,b.w};
  u16* d = dst + tid * 8;
  #pragma unroll
  for (int i = 0; i < 8; i++) {
    float q = rintf(v[i] / s);
    q = fminf(fmaxf(q, -1.f), 1.f);
    d[i] = f2bf(q * s);
  }
}

// ---------------- fp32 -> bf16 ----------------
__global__ __launch_bounds__(256) void cvt_bf16(const float* __restrict__ in,
                                                u16* __restrict__ out) {
  size_t i = ((size_t)blockIdx.x * 256 + threadIdx.x) * 4;
  float4 v = *(const float4*)(in + i);
  u16x4 o;
  o.x = f2bf(v.x); o.y = f2bf(v.y); o.z = f2bf(v.z); o.w = f2bf(v.w);
  *(u16x4*)(out + i) = o;
}

// ---------------- GEMM  C[M][N] = A[M][K] * B[N][K]^T  (bf16 in, fp32 out) -------
__global__ __launch_bounds__(256) void gemm_bt(const u16* __restrict__ A,
                                               const u16* __restrict__ B,
                                               float* __restrict__ C,
                                               int M, int N, int K) {
  __shared__ u16 sA[128 * 32];
  __shared__ u16 sB[128 * 32];
  const int tid = threadIdx.x;
  const int lane = tid & 63;
  const int wid = tid >> 6;
  const int lr = lane & 15, lq = lane >> 4;
  const int wm = (wid >> 1) * 64, wn = (wid & 1) * 64;
  const size_t m0 = (size_t)blockIdx.y * 128, n0 = (size_t)blockIdx.x * 128;

  const int r0 = tid >> 2, c0 = (tid & 3) * 8;
  const u16* Ab0 = A + (m0 + r0) * (size_t)K + c0;
  const u16* Ab1 = A + (m0 + 64 + r0) * (size_t)K + c0;
  const u16* Bb0 = B + (n0 + r0) * (size_t)K + c0;
  const u16* Bb1 = B + (n0 + 64 + r0) * (size_t)K + c0;
  u16* sA0 = &sA[tid * 8];
  u16* sA1 = &sA[(256 + tid) * 8];
  u16* sB0 = &sB[tid * 8];
  u16* sB1 = &sB[(256 + tid) * 8];

  f32x4 acc[4][4] = {};

  for (int kt = 0; kt < K; kt += 32) {
    async16(Ab0 + kt, sA0);
    async16(Ab1 + kt, sA1);
    async16(Bb0 + kt, sB0);
    async16(Bb1 + kt, sB1);
    __syncthreads();
    s16x8 af[4], bf[4];
    #pragma unroll
    for (int mt = 0; mt < 4; mt++)
      af[mt] = *(const s16x8*)&sA[(wm + mt * 16 + lr) * 32 + lq * 8];
    #pragma unroll
    for (int nt = 0; nt < 4; nt++)
      bf[nt] = *(const s16x8*)&sB[(wn + nt * 16 + lr) * 32 + lq * 8];
    #pragma unroll
    for (int mt = 0; mt < 4; mt++)
      #pragma unroll
      for (int nt = 0; nt < 4; nt++)
        acc[mt][nt] = __builtin_amdgcn_mfma_f32_16x16x32_bf16(af[mt], bf[nt], acc[mt][nt], 0, 0, 0);
    __syncthreads();
  }
  #pragma unroll
  for (int mt = 0; mt < 4; mt++)
    #pragma unroll
    for (int nt = 0; nt < 4; nt++)
      #pragma unroll
      for (int r = 0; r < 4; r++) {
        size_t m = m0 + wm + mt * 16 + lq * 4 + r;
        size_t n = n0 + wn + nt * 16 + lr;
        C[m * (size_t)N + n] = acc[mt][nt][r];
      }
}

// ---------------- rmsnorm + rope; K written swizzled for attn staging --------
// KH tile (8192 u16) granule layout: G = kc*256 + kr*4 + (gk ^ ((kr>>1)&3)),
// content K[kv=kr][d = kc*32 + gk*8 + e] at u16 G*8+e.
__global__ __launch_bounds__(256) void prep_qk(const float* __restrict__ qkv,
                                               const float* __restrict__ qgain,
                                               u16* __restrict__ Qh,
                                               u16* __restrict__ Kh) {
  const int s = blockIdx.y;
  const int j = blockIdx.x * 4 + (threadIdx.x >> 6);
  const int t = threadIdx.x & 63;
  const float* row = qkv + (size_t)s * 3072 + (size_t)j * 128;
  float x1 = row[t], x2 = row[t + 64];
  float ss = x1 * x1 + x2 * x2;
  #pragma unroll
  for (int off = 1; off < 64; off <<= 1) ss += __shfl_xor(ss, off, 64);
  float rn = rsqrtf(ss * (1.0f / 128.0f) + 1.1920929e-07f);
  float invf = exp2f(-(float)t * 0.20762050593048096f);  // log2(10000)/64
  float ang = (float)s * invf;
  float sn, c;
  __sincosf(ang, &sn, &c);
  if (j < 16) {
    float g = qgain[j] * 0.12751738f;   // (1/sqrt(128)) * log2(e)
    float q1 = x1 * rn, q2 = x2 * rn;
    float o1 = (q1 * c + q2 * sn) * g;
    float o2 = (-q1 * sn + q2 * c) * g;
    u16* dst = Qh + ((size_t)j * 4096 + s) * 128;
    dst[t] = f2bf(o1); dst[t + 64] = f2bf(o2);
  } else {
    const int kvh = j - 16;
    float k1 = x1 * rn, k2 = x2 * rn;
    float o1 = k1 * c + k2 * sn;
    float o2 = -k1 * sn + k2 * c;
    const int tt = s >> 6, kr = s & 63;
    const int sw = (kr >> 1) & 3;
    u16* tile = Kh + ((size_t)kvh * 64 + tt) * 8192;
    // d1 = t
    { int d = t;      int kc = d >> 5, gk = (d >> 3) & 3, e = d & 7;
      tile[(kc * 256 + kr * 4 + (gk ^ sw)) * 8 + e] = f2bf(o1); }
    // d2 = t + 64
    { int d = t + 64; int kc = d >> 5, gk = (d >> 3) & 3, e = d & 7;
      tile[(kc * 256 + kr * 4 + (gk ^ sw)) * 8 + e] = f2bf(o2); }
  }
}

// ---------------- V transpose into x32-PV staging layout ---------------------
// VT tile (8192 u16): row d (0..127) of 64 u16. Column for seq-kv (bits b5..b0):
// col = [b4 b3 b2 b5 b1 b0]; granule gv = col>>3 stored at gv^(d&7).
__global__ __launch_bounds__(256) void vtrans(const float* __restrict__ qkv,
                                              u16* __restrict__ Vtg) {
  __shared__ float tile[64][67];
  const int tid = threadIdx.x;
  const int s0 = blockIdx.y * 64;
  const int c0 = blockIdx.x * 64;
  #pragma unroll
  for (int it = 0; it < 4; it++) {
    int i = it * 256 + tid;
    int r = i >> 4, c = (i & 15) * 4;
    float4 v = *(const float4*)(qkv + (size_t)(s0 + r) * 3072 + 2560 + c0 + c);
    tile[r][c] = v.x; tile[r][c + 1] = v.y; tile[r][c + 2] = v.z; tile[r][c + 3] = v.w;
  }
  __syncthreads();
  #pragma unroll
  for (int it = 0; it < 2; it++) {
    int i = it * 256 + tid;
    int dl = i >> 3, sc = (i & 7) * 8;        // sc = kv group of 8
    int cglob = c0 + dl;
    int kvh = cglob >> 7, d = cglob & 127;
    int tt = s0 >> 6;
    int qb = sc >> 3;                          // bits [b5 b4 b3]
    int glo = ((qb >> 1) & 1) * 4 + (qb & 1) * 2;
    int ghi = glo + 1;
    int ebase = ((qb >> 2) & 1) * 4;
    int x = d & 7;
    size_t rowbase = (((size_t)kvh * 64 + tt) * 128 + d) * 64;
    u16 lo[4], hi[4];
    #pragma unroll
    for (int jj = 0; jj < 4; jj++) lo[jj] = f2bf(tile[sc + jj][dl]);
    #pragma unroll
    for (int jj = 0; jj < 4; jj++) hi[jj] = f2bf(tile[sc + 4 + jj][dl]);
    *(s16x4*)&Vtg[rowbase + (size_t)((glo ^ x) * 8 + ebase)] = *(s16x4*)lo;
    *(s16x4*)&Vtg[rowbase + (size_t)((ghi ^ x) * 8 + ebase)] = *(s16x4*)hi;
  }
}

// ---------------- flash attention v8: dbuf prefetch + x32 PV -----------------
// Uniform 16/17-step units, S^T form, P in registers (x32 repack), stale-max,
// deferred l. NEW: double-buffered LDS with raw s_barrier + s_waitcnt vmcnt(8)
// prefetch pipeline -- staging latency of step t+1 hidden behind compute of t.
#define SEG(qt,a,b,s) ((unsigned)((qt)|((a)<<5)|((b)<<11)|((s)<<18)))
__constant__ unsigned SEGTAB[128] = {
  SEG(0,0,2,127),   SEG(15,0,15,14),
  SEG(15,15,32,15), 0,
  SEG(1,0,4,127),   SEG(14,0,13,12),
  SEG(14,13,30,13), 0,
  SEG(2,0,6,127),   SEG(13,0,11,10),
  SEG(13,11,28,11), 0,
  SEG(3,0,8,127),   SEG(12,0,9,8),
  SEG(12,9,26,9),   0,
  SEG(4,0,10,127),  SEG(11,0,7,6),
  SEG(11,7,24,7),   0,
  SEG(5,0,12,127),  SEG(10,0,5,4),
  SEG(10,5,22,5),   0,
  SEG(6,0,14,127),  SEG(9,0,3,2),
  SEG(9,3,20,3),    0,
  SEG(7,0,16,127),  SEG(8,0,1,0),
  SEG(8,1,18,1),    0,
  SEG(16,0,16,16),  0,
  SEG(16,16,33,17), 0,
  SEG(16,33,34,18), SEG(17,0,15,19),
  SEG(17,15,31,20), 0,
  SEG(17,31,36,21), SEG(18,0,12,22),
  SEG(18,12,28,23), 0,
  SEG(18,28,38,24), SEG(19,0,6,25),
  SEG(19,6,23,26),  0,
  SEG(19,23,39,27), 0,
  SEG(19,39,40,28), SEG(20,0,15,29),
  SEG(20,15,32,30), 0,
  SEG(20,32,42,31), SEG(21,0,6,32),
  SEG(21,6,22,33),  0,
  SEG(21,22,39,34), 0,
  SEG(21,39,44,35), SEG(22,0,11,36),
  SEG(22,11,27,37), 0,
  SEG(22,27,44,38), 0,
  SEG(22,44,46,39), SEG(23,0,14,40),
  SEG(23,14,30,41), 0,
  SEG(23,30,47,42), 0,
  SEG(23,47,48,43), SEG(24,0,15,44),
  SEG(24,15,31,45), 0,
  SEG(24,31,48,46), 0,
  SEG(24,48,50,47), SEG(25,0,14,48),
  SEG(25,14,30,49), 0,
  SEG(25,30,47,50), 0,
  SEG(25,47,52,51), SEG(26,0,11,52),
  SEG(26,11,27,53), 0,
  SEG(26,27,44,54), 0,
  SEG(26,44,54,55), SEG(27,0,6,56),
  SEG(27,6,22,57),  0,
  SEG(27,22,39,58), 0,
  SEG(27,39,55,59), 0,
  SEG(27,55,56,60), SEG(28,0,15,61),
  SEG(28,15,32,62), 0,
  SEG(28,32,48,63), 0,
  SEG(28,48,58,64), SEG(29,0,6,65),
  SEG(29,6,23,66),  0,
  SEG(29,23,39,67), 0,
  SEG(29,39,55,68), 0,
  SEG(29,55,60,69), SEG(30,0,12,70),
  SEG(30,12,28,71), 0,
  SEG(30,28,44,72), 0,
  SEG(30,44,61,73), 0,
  SEG(30,61,62,74), SEG(31,0,15,75),
  SEG(31,15,31,76), 0,
  SEG(31,31,48,77), 0,
  SEG(31,48,64,78), 0,
};
__constant__ unsigned char CBASE[24] = {0,2,4,6,8,10,12,14, 16,19,22,25,29,32,36,40, 44,48,52,56,61,65,70,75};
__constant__ unsigned char CCNT[24]  = {2,2,2,2,2,2,2,2, 3,3,3,4,3,4,4,4, 4,4,4,5,4,5,5,4};

__global__ __launch_bounds__(256, 2) void attn(const u16* __restrict__ Q,
                                               const u16* __restrict__ Kh,
                                               const u16* __restrict__ Vt,
                                               u16* __restrict__ Y,
                                               u16* __restrict__ Opart,
                                               float* __restrict__ MLpart) {
  const int tid = threadIdx.x, lane = tid & 63, wid = tid >> 6;
  const int lr = lane & 15, lq = lane >> 4;
  const int b = blockIdx.x;
  const int h = b & 15, unit = b >> 4;
  const int kvh = h >> 2;

  // double buffer: [buf][ K 8192 u16 | V 8192 u16 ]
  __shared__ u16 sKV[2][16384];

  const u16* Kbase = Kh + (size_t)kvh * 64 * 8192;
  const u16* Vbase = Vt + (size_t)kvh * 64 * 8192;

  const int kx8 = (lq ^ ((lr >> 1) & 3)) * 8;         // K read swizzle
  const int vo0 = ((lq ^ (lr & 7)) << 3);             // V chunk0 granule
  const int vo1 = (((4 + lq) ^ (lr & 7)) << 3);       // V chunk1 granule

  #pragma unroll 1
  for (int si = 0; si < 2; ++si) {
    const unsigned sd = SEGTAB[unit * 2 + si];
    const int qt = sd & 31;
    const int t0 = (sd >> 5) & 63;
    const int t1 = (sd >> 11) & 127;
    const int slot = (sd >> 18) & 127;
    if (t1 <= t0) continue;
    const int qbase = qt * 128;
    const int nst = t1 - t0;

    // prologue: stage t0 into buf0 (8 vm ops / thread)
    {
      const u16* Kt = Kbase + (size_t)t0 * 8192;
      const u16* Vtt = Vbase + (size_t)t0 * 8192;
      #pragma unroll
      for (int it = 0; it < 4; it++) {
        int off = it * 2048 + tid * 8;
        async16(Kt + off, &sKV[0][off]);
        async16(Vtt + off, &sKV[0][8192 + off]);
      }
    }

    s16x8 qf[2][4];
    #pragma unroll
    for (int f = 0; f < 2; f++) {
      const u16* qp = Q + ((size_t)h * 4096 + qbase + wid * 32 + f * 16 + lr) * 128 + lq * 8;
      #pragma unroll
      for (int kc = 0; kc < 4; kc++) qf[f][kc] = *(const s16x8*)(qp + kc * 32);
    }

    f32x4 oacc[2][8] = {};
    f32x4 lacc[2] = {};
    float mrow[2] = {-1e30f, -1e30f};

    for (int t2 = 0; t2 < nst; ++t2) {
      const int t = t0 + t2;
      const int cur = t2 & 1;
      if (t2 + 1 < nst) {
        // prefetch next tile into other buffer, then wait only own t-loads
        const u16* Kt = Kbase + (size_t)(t + 1) * 8192;
        const u16* Vtt = Vbase + (size_t)(t + 1) * 8192;
        u16* dstb = &sKV[cur ^ 1][0];
        #pragma unroll
        for (int it = 0; it < 4; it++) {
          int off = it * 2048 + tid * 8;
          async16(Kt + off, dstb + off);
          async16(Vtt + off, dstb + 8192 + off);
        }
        asm volatile("s_waitcnt vmcnt(8)" ::: "memory");
      } else {
        asm volatile("s_waitcnt vmcnt(0)" ::: "memory");
      }
      asm volatile("s_barrier" ::: "memory");   // all waves: tile t resident

      const u16* bufK = &sKV[cur][0];
      const u16* bufV = &sKV[cur][8192];

      // S^T = K · Q^T  (x32)
      f32x4 sacc[2][4] = {};
      #pragma unroll
      for (int nt = 0; nt < 4; nt++) {
        const int rowoff = (nt * 16 + lr) * 32 + kx8;
        #pragma unroll
        for (int kc = 0; kc < 4; kc++) {
          s16x8 kf = *(const s16x8*)&bufK[kc * 2048 + rowoff];
          sacc[0][nt] = __builtin_amdgcn_mfma_f32_16x16x32_bf16(kf, qf[0][kc], sacc[0][nt], 0, 0, 0);
          sacc[1][nt] = __builtin_amdgcn_mfma_f32_16x16x32_bf16(kf, qf[1][kc], sacc[1][nt], 0, 0, 0);
        }
      }

      if (t >= 2 * qt) {   // causal mask: kv > q
        #pragma unroll
        for (int f = 0; f < 2; f++) {
          int qg = qbase + wid * 32 + f * 16 + lr;
          #pragma unroll
          for (int nt = 0; nt < 4; nt++) {
            int kv0 = t * 64 + nt * 16 + lq * 4;
            #pragma unroll
            for (int r = 0; r < 4; r++)
              if (kv0 + r > qg) sacc[f][nt][r] = -1e30f;
          }
        }
      }

      // per-lane max; rescale only past stale-max margin
      float pm[2];
      #pragma unroll
      for (int f = 0; f < 2; f++) {
        float a = fmaxf(fmaxf(sacc[f][0][0], sacc[f][0][1]), fmaxf(sacc[f][0][2], sacc[f][0][3]));
        float bb = fmaxf(fmaxf(sacc[f][1][0], sacc[f][1][1]), fmaxf(sacc[f][1][2], sacc[f][1][3]));
        float cc = fmaxf(fmaxf(sacc[f][2][0], sacc[f][2][1]), fmaxf(sacc[f][2][2], sacc[f][2][3]));
        float dd = fmaxf(fmaxf(sacc[f][3][0], sacc[f][3][1]), fmaxf(sacc[f][3][2], sacc[f][3][3]));
        pm[f] = fmaxf(fmaxf(a, bb), fmaxf(cc, dd));
      }
      if (__any((pm[0] > mrow[0] + 3.0f) || (pm[1] > mrow[1] + 3.0f))) {
        #pragma unroll
        for (int f = 0; f < 2; f++) {
          float mn = pm[f];
          mn = fmaxf(mn, __shfl_xor(mn, 16, 64));
          mn = fmaxf(mn, __shfl_xor(mn, 32, 64));
          mn = fmaxf(mn, mrow[f]);
          float al = exp2f(mrow[f] - mn);
          mrow[f] = mn;
          lacc[f] *= al;
          #pragma unroll
          for (int dt = 0; dt < 8; dt++)
            #pragma unroll
            for (int r = 0; r < 4; r++) oacc[f][dt][r] *= al;
        }
      }

      // P^T = exp2(S^T - m), repacked for x32 B-frags: pf[c][j], j=(a,r), nt=2a+c
      s16x8 pf[2][2];
      #pragma unroll
      for (int f = 0; f < 2; f++)
        #pragma unroll
        for (int c = 0; c < 2; c++)
          #pragma unroll
          for (int j = 0; j < 8; j++) {
            int nt = 2 * (j >> 2) + c;
            int r = j & 3;
            union { float fv; unsigned u; } pu;
            pu.fv = exp2f(sacc[f][nt][r] - mrow[f]);
            lacc[f][r] += pu.fv;
            pf[f][c][j] = (short)(pu.u >> 16);
          }

      // O^T += V^T · P^T  (x32, 2 chunks)
      #pragma unroll
      for (int dt = 0; dt < 8; dt++) {
        const u16* vrow = bufV + (dt * 16 + lr) * 64;
        s16x8 va0 = *(const s16x8*)(vrow + vo0);
        s16x8 va1 = *(const s16x8*)(vrow + vo1);
        oacc[0][dt] = __builtin_amdgcn_mfma_f32_16x16x32_bf16(va0, pf[0][0], oacc[0][dt], 0, 0, 0);
        oacc[1][dt] = __builtin_amdgcn_mfma_f32_16x16x32_bf16(va0, pf[1][0], oacc[1][dt], 0, 0, 0);
        oacc[0][dt] = __builtin_amdgcn_mfma_f32_16x16x32_bf16(va1, pf[0][1], oacc[0][dt], 0, 0, 0);
        oacc[1][dt] = __builtin_amdgcn_mfma_f32_16x16x32_bf16(va1, pf[1][1], oacc[1][dt], 0, 0, 0);
      }
      // all waves done reading buf cur before next iter's prefetch overwrites it
      asm volatile("s_waitcnt lgkmcnt(0)\n\ts_barrier" ::: "memory");
    }

    // final l: reduce regs then cross-lane (once per segment)
    float lrow[2];
    #pragma unroll
    for (int f = 0; f < 2; f++) {
      float s4 = (lacc[f][0] + lacc[f][1]) + (lacc[f][2] + lacc[f][3]);
      s4 += __shfl_xor(s4, 16, 64);
      s4 += __shfl_xor(s4, 32, 64);
      lrow[f] = s4;
    }

    // epilogue: lane layout q = wid*32 + f*16 + lr, d = dt*16 + lq*4 + r
    if (slot == 127) {
      #pragma unroll
      for (int f = 0; f < 2; f++) {
        float linv = 1.0f / lrow[f];
        int qg = qbase + wid * 32 + f * 16 + lr;
        #pragma unroll
        for (int dt = 0; dt < 8; dt++) {
          u16 tmp[4];
          #pragma unroll
          for (int r = 0; r < 4; r++) tmp[r] = f2bf(oacc[f][dt][r] * linv);
          *(s16x4*)&Y[(size_t)qg * 2048 + h * 128 + dt * 16 + lq * 4] = *(s16x4*)tmp;
        }
      }
    } else {
      const int gslot = h * 79 + slot;
      u16* Op = Opart + (size_t)gslot * 16384;
      #pragma unroll
      for (int f = 0; f < 2; f++) {
        int row = wid * 32 + f * 16 + lr;
        #pragma unroll
        for (int dt = 0; dt < 8; dt++) {
          u16 tmp[4];
          #pragma unroll
          for (int r = 0; r < 4; r++) tmp[r] = f2bf(oacc[f][dt][r]);
          *(s16x4*)&Op[row * 128 + dt * 16 + lq * 4] = *(s16x4*)tmp;
        }
        if (lq == 0) {
          MLpart[(size_t)gslot * 256 + row * 2]     = mrow[f];
          MLpart[(size_t)gslot * 256 + row * 2 + 1] = lrow[f];
        }
      }
    }
  }
}

// ---------------- combine: merge 2-5 partials per split tile -> Y ----------
__global__ __launch_bounds__(256) void combine(const u16* __restrict__ Op,
                                               const float* __restrict__ ML,
                                               u16* __restrict__ Y) {
  const int b = blockIdx.x;
  const int qt = 8 + (b >> 4), h = b & 15;
  const int base = CBASE[qt - 8], n = CCNT[qt - 8];
  const int gbase = h * 79 + base;
  const int tid = threadIdx.x;
  const int row = tid >> 1, half = (tid & 1) * 64;

  float m[5], l[5];
  float mstar = -3e38f;
  for (int i = 0; i < n; i++) {
    m[i] = ML[(size_t)(gbase + i) * 256 + row * 2];
    l[i] = ML[(size_t)(gbase + i) * 256 + row * 2 + 1];
    mstar = fmaxf(mstar, m[i]);
  }
  float w[5], wsum = 0.f;
  for (int i = 0; i < n; i++) { w[i] = exp2f(m[i] - mstar); wsum += l[i] * w[i]; }
  float inv = 1.0f / wsum;

  float acc[64] = {};
  for (int i = 0; i < n; i++) {
    const u16* o = Op + (size_t)(gbase + i) * 16384 + row * 128 + half;
    float wi = w[i];
    #pragma unroll
    for (int c = 0; c < 64; c += 8) {
      s16x8 a = *(const s16x8*)(o + c);
      #pragma unroll
      for (int jj = 0; jj < 8; jj++) acc[c + jj] += wi * bf2f((u16)a[jj]);
    }
  }
  u16* dst = Y + ((size_t)qt * 128 + row) * 2048 + h * 128 + half;
  #pragma unroll
  for (int c = 0; c < 64; c += 8) {
    u16 tmp[8];
    #pragma unroll
    for (int jj = 0; jj < 8; jj++) tmp[jj] = f2bf(acc[c + jj] * inv);
    *(s16x8*)(dst + c) = *(s16x8*)tmp;
  }
}

// ---------------- launch ----------------
extern "C" void kernel_launch(void* const* d_in, const int* in_sizes, int n_in,
                              void* d_out, int out_size, void* d_ws, size_t ws_size,
                              hipStream_t stream) {
  const float* x  = (const float*)d_in[0];
  const float* wq = (const float*)d_in[1];
  const float* wk = (const float*)d_in[2];
  const float* wv = (const float*)d_in[3];
  const float* wp = (const float*)d_in[4];
  const float* qg = (const float*)d_in[5];
  float* out = (float*)d_out;
  char* ws = (char*)d_ws;

  u16*   XB    = (u16*)(ws + OFF_XB);
  u16*   WQKV  = (u16*)(ws + OFF_WQKV);
  u16*   WP    = (u16*)(ws + OFF_WP);
  float* QKV   = (float*)(ws + OFF_QKV);
  u16*   QH    = XB;                      // reuse after GEMM1
  u16*   KH    = (u16*)(ws + OFF_KH);     // reuse of WQKV region after GEMM1
  u16*   VT    = (u16*)(ws + OFF_VT);
  float* MLP   = (float*)(ws + OFF_ML);
  u16*   OPART = (u16*)(ws + OFF_QKV);    // reuse after prep/vtrans
  u16*   Yb    = (u16*)(ws + OFF_Y);

  quant_all<<<5120, 256, 0, stream>>>(wq, wk, wv, wp, WQKV, WP);
  cvt_bf16<<<8192, 256, 0, stream>>>(x, XB);
  gemm_bt<<<dim3(24, 32), 256, 0, stream>>>(XB, WQKV, QKV, 4096, 3072, 2048);
  prep_qk<<<dim3(5, 4096), 256, 0, stream>>>(QKV, qg, QH, KH);
  vtrans<<<dim3(8, 64), 256, 0, stream>>>(QKV, VT);
  attn<<<1024, 256, 0, stream>>>(QH, KH, VT, Yb, OPART, MLP);
  combine<<<384, 256, 0, stream>>>(OPART, MLP, Yb);
  gemm_bt<<<dim3(16, 32), 256, 0, stream>>>(Yb, WP, out, 4096, 2048, 2048);
}